// Round 4
// baseline (88.415 us; speedup 1.0000x reference)
//
#include <hip/hip_runtime.h>

// Problem constants
#define NB 4      // batch
#define CI 256    // input channels
#define HH 64
#define WW 64
#define MC 64     // compressed channels
#define HS 128    // H*2
#define WS_ 128   // W*2
#define HW 4096   // HH*WW

typedef __attribute__((ext_vector_type(8))) short short8v;   // 8 bf16 (4 VGPRs)
typedef __attribute__((ext_vector_type(4))) float floatx4;   // MFMA C/D

__device__ inline unsigned short f2bf(float f) {
  union { float f; unsigned u; } v; v.f = f;
  unsigned r = v.u + 0x7FFFu + ((v.u >> 16) & 1u);   // RNE
  return (unsigned short)(r >> 16);
}

// ---------------------------------------------------------------------------
// Prep: rearrange weights into MFMA A-fragment layout (bf16).
// Aw1[ks][o:64][kl:32]  = w_comp[o][ks*32+kl]                (8 k-steps)
// Aw2[ks][o:112][kl:32] = w_enc[o][m][tap], tap=ks>>1, m=(ks&1)*32+kl
// ---------------------------------------------------------------------------
__global__ __launch_bounds__(256) void prep_kernel(
    const float* __restrict__ w_comp, const float* __restrict__ w_enc,
    unsigned short* __restrict__ Aw1, unsigned short* __restrict__ Aw2) {
  int i = blockIdx.x * 256 + threadIdx.x;
  if (i < 16384) {                       // 8*64*32
    int kl = i & 31, o = (i >> 5) & 63, ks = i >> 11;
    Aw1[i] = f2bf(w_comp[o * 256 + ks * 32 + kl]);
  } else if (i < 16384 + 64512) {        // 18*112*32
    int j = i - 16384;
    int kl = j & 31, o = (j >> 5) % 112, ks = (j >> 5) / 112;
    int t = ks >> 1, m = (ks & 1) * 32 + kl;
    Aw2[j] = (o < 100) ? f2bf(w_enc[o * 576 + m * 9 + t]) : (unsigned short)0;
  }
}

// ---------------------------------------------------------------------------
// Kernel 1: 1x1 conv via MFMA, K-split 2.
// Block = 512 threads = 8 waves: 4 pixel-tiles x 2 K-halves (128 ch each).
// Partial sums exchanged via LDS (stride 17 = conflict-free), kh==0 wave
// finishes bias + bf16 channel-last store.
// ---------------------------------------------------------------------------
__global__ __launch_bounds__(512, 1) void conv1x1_mfma(
    const float* __restrict__ x, const unsigned short* __restrict__ Aw1,
    const float* __restrict__ b_comp, unsigned short* __restrict__ comp_cl) {
  __shared__ float pacc[4][64][17];
  int tid = threadIdx.x;
  int wid = tid >> 6, lane = tid & 63;
  int tileid = wid & 3, kh = wid >> 2;
  int Nt = blockIdx.x * 4 + tileid;       // 0..1023
  int n = Nt >> 8, pixbase = (Nt & 255) * 16;
  int l15 = lane & 15, g = lane >> 4;
  int pix = pixbase + l15;

  floatx4 acc[4];
#pragma unroll
  for (int ot = 0; ot < 4; ++ot) acc[ot] = (floatx4){0.f, 0.f, 0.f, 0.f};

  const float* xb = x + (size_t)n * CI * HW + pix;
  const unsigned short* ab = Aw1 + l15 * 32 + g * 8;

#pragma unroll
  for (int s = 0; s < 4; ++s) {
    int ks = kh * 4 + s;
    int c0 = ks * 32 + g * 8;
    short8v bfrag;
#pragma unroll
    for (int j = 0; j < 8; ++j)
      bfrag[j] = (short)f2bf(xb[(size_t)(c0 + j) * HW]);
#pragma unroll
    for (int ot = 0; ot < 4; ++ot) {
      short8v af = *(const short8v*)(ab + (ks * 64 + ot * 16) * 32);
      acc[ot] = __builtin_amdgcn_mfma_f32_16x16x32_bf16(af, bfrag, acc[ot], 0, 0, 0);
    }
  }

  if (kh == 1) {
#pragma unroll
    for (int ot = 0; ot < 4; ++ot)
#pragma unroll
      for (int r = 0; r < 4; ++r) pacc[tileid][lane][ot * 4 + r] = acc[ot][r];
  }
  __syncthreads();
  if (kh == 0) {
    unsigned short* cp = comp_cl + ((size_t)(n * HW + pix)) * 64;
#pragma unroll
    for (int ot = 0; ot < 4; ++ot) {
      const float4 bv = *(const float4*)(b_comp + ot * 16 + g * 4);
      float v0 = acc[ot][0] + pacc[tileid][lane][ot * 4 + 0] + bv.x;
      float v1 = acc[ot][1] + pacc[tileid][lane][ot * 4 + 1] + bv.y;
      float v2 = acc[ot][2] + pacc[tileid][lane][ot * 4 + 2] + bv.z;
      float v3 = acc[ot][3] + pacc[tileid][lane][ot * 4 + 3] + bv.w;
      unsigned h01 = (unsigned)f2bf(v0) | ((unsigned)f2bf(v1) << 16);
      unsigned h23 = (unsigned)f2bf(v2) | ((unsigned)f2bf(v3) << 16);
      *(int2*)(cp + ot * 16 + g * 4) = make_int2((int)h01, (int)h23);
    }
  }
}

// ---------------------------------------------------------------------------
// Kernel 2: 3x3 conv (64->100) + pixel-shuffle + softmax(25), K-split 2.
// Block = 512 threads = 8 waves: 4 pixel-tiles x 2 K-halves (ks 0..8 / 9..17).
// Partials via LDS (stride 29); kh==0 wave does bias + softmax + store.
// ---------------------------------------------------------------------------
__global__ __launch_bounds__(512, 1) void kenc_mfma(
    const unsigned short* __restrict__ comp_cl,
    const unsigned short* __restrict__ Aw2,
    const float* __restrict__ b_enc, float* __restrict__ wbuf_q) {
  __shared__ float pacc[4][64][29];
  int tid = threadIdx.x;
  int wid = tid >> 6, lane = tid & 63;
  int tileid = wid & 3, kh = wid >> 2;
  int Nt = blockIdx.x * 4 + tileid;       // 0..1023
  int n = Nt >> 8, pixbase = (Nt & 255) * 16;
  int l15 = lane & 15, g = lane >> 4;
  int pix = pixbase + l15;
  int y = pix >> 6, xcol = pix & 63;

  bool vm[9];
  int sh9[9];
#pragma unroll
  for (int t = 0; t < 9; ++t) {
    int dy = t / 3, dx = t % 3;
    vm[t] = ((unsigned)(y + dy - 1) < 64u) && ((unsigned)(xcol + dx - 1) < 64u);
    sh9[t] = (dy - 1) * 64 + (dx - 1);
  }

  floatx4 acc[7];
#pragma unroll
  for (int ot = 0; ot < 7; ++ot) acc[ot] = (floatx4){0.f, 0.f, 0.f, 0.f};

  const unsigned short* cb = comp_cl + (size_t)n * HW * 64;
  const unsigned short* ab = Aw2 + l15 * 32 + g * 8;
  const short8v zv = {0, 0, 0, 0, 0, 0, 0, 0};

#pragma unroll
  for (int s = 0; s < 9; ++s) {
    int ks = kh * 9 + s;
    int t = ks >> 1, mh = ks & 1;
    const unsigned short* bp = cb + (pix + sh9[t]) * 64 + mh * 32 + g * 8;
    short8v bfrag = vm[t] ? *(const short8v*)bp : zv;
#pragma unroll
    for (int ot = 0; ot < 7; ++ot) {
      short8v af = *(const short8v*)(ab + (ks * 112 + ot * 16) * 32);
      acc[ot] = __builtin_amdgcn_mfma_f32_16x16x32_bf16(af, bfrag, acc[ot], 0, 0, 0);
    }
  }

  if (kh == 1) {
#pragma unroll
    for (int ot = 0; ot < 7; ++ot)
#pragma unroll
      for (int r = 0; r < 4; ++r) pacc[tileid][lane][ot * 4 + r] = acc[ot][r];
  }
  __syncthreads();
  if (kh == 0) {
#pragma unroll
    for (int ot = 0; ot < 7; ++ot) {
      int ob = ot * 16 + g * 4; if (ob > 96) ob = 96;
      const float4 bv = *(const float4*)(b_enc + ob);
      acc[ot][0] += pacc[tileid][lane][ot * 4 + 0] + bv.x;
      acc[ot][1] += pacc[tileid][lane][ot * 4 + 1] + bv.y;
      acc[ot][2] += pacc[tileid][lane][ot * 4 + 2] + bv.z;
      acc[ot][3] += pacc[tileid][lane][ot * 4 + 3] + bv.w;
    }

    // softmax over kk = ot*4+g (valid: ot<6 always, ot==6 only g==0)
#pragma unroll
    for (int r = 0; r < 4; ++r) {
      float m = acc[0][r];
#pragma unroll
      for (int ot = 1; ot < 6; ++ot) m = fmaxf(m, acc[ot][r]);
      if (g == 0) m = fmaxf(m, acc[6][r]);
      m = fmaxf(m, __shfl_xor(m, 16));
      m = fmaxf(m, __shfl_xor(m, 32));
      float s = 0.f;
      float e[7];
#pragma unroll
      for (int ot = 0; ot < 7; ++ot) {
        bool val = (ot < 6) || (g == 0);
        e[ot] = val ? __expf(acc[ot][r] - m) : 0.f;
        s += e[ot];
      }
      s += __shfl_xor(s, 16);
      s += __shfl_xor(s, 32);
      float inv = 1.f / s;
      float* wq = wbuf_q + ((size_t)(n * 4 + r) * HW + pix) * 25;
#pragma unroll
      for (int ot = 0; ot < 7; ++ot)
        if ((ot < 6) || (g == 0)) wq[ot * 4 + g] = e[ot] * inv;
    }
  }
}

// ---------------------------------------------------------------------------
// Kernel 3: reassembly v3.
// Block = 4x16 output tile x 128 channels (cg half); LDS 36 KB -> 4 blocks/CU.
// Thread = 2 adjacent outputs (ox0, ox0+1: same input window, q-pair) x
// 16 channel-iters -> only 50 weight VGPRs (asm-pinned), ~80 VGPR total,
// 4 waves/SIMD. 25 b32 LDS reads (<=2-way) + 50 FMA per iter; float2 stores.
// ---------------------------------------------------------------------------
__global__ __launch_bounds__(256, 4) void reassembly_kernel(
    const float* __restrict__ x, const float* __restrict__ wbuf,
    float* __restrict__ out) {
  __shared__ float xpatch[128 * 72];    // [c][r:6][col:12]
  int tid = threadIdx.x;
  int bid = blockIdx.x;                 // tile(256) | n(4) | cg(2)
  int tile = bid & 255;
  int n = (bid >> 8) & 3;
  int cg = bid >> 10;
  int tyi = tile >> 3, txi = tile & 7;  // 32 x 8 tiles of 4x16 outputs
  int ty0 = tyi * 4, tx0 = txi * 16;
  int h0 = ty0 >> 1, w0 = tx0 >> 1;     // input block base (2 rows x 8 cols)

  const float* xb = x + (size_t)(n * CI + cg * 128) * HW;
  bool interior = (tyi >= 1) && (tyi <= 30) && (txi >= 1) && (txi <= 6);

  if (interior) {
#pragma unroll
    for (int j = 0; j < 9; ++j) {
      int f = tid + 256 * j;            // f4 index 0..2303 (128*18)
      int c = f / 18, rem = f - c * 18;
      int r = rem / 3, h = rem - r * 3;
      const float* gp = xb + (size_t)c * HW + (h0 - 2 + r) * WW + (w0 - 2 + h * 4);
      float2 lo = *(const float2*)(gp);
      float2 hi = *(const float2*)(gp + 2);
      *(float4*)(xpatch + c * 72 + r * 12 + h * 4) =
          make_float4(lo.x, lo.y, hi.x, hi.y);
    }
  } else {
#pragma unroll
    for (int j = 0; j < 9; ++j) {
      int f = tid + 256 * j;
      int c = f / 18, rem = f - c * 18;
      int r = rem / 3, h = rem - r * 3;
      int gh = h0 - 2 + r;
      float vv[4];
#pragma unroll
      for (int e = 0; e < 4; ++e) {
        int gw = w0 - 2 + h * 4 + e;
        vv[e] = (((unsigned)gh < 64u) && ((unsigned)gw < 64u))
                    ? xb[(size_t)c * HW + gh * WW + gw] : 0.f;
      }
      *(float4*)(xpatch + c * 72 + r * 12 + h * 4) =
          make_float4(vv[0], vv[1], vv[2], vv[3]);
    }
  }

  // Thread mapping: 8 channel-slots x 32 pixel-pairs
  int cslot = tid >> 5;                 // 0..7
  int pp = tid & 31;                    // qy(2b) | pxpair(3b)
  int qy = pp >> 3, pxpair = pp & 7;
  int oy = ty0 + qy;
  int ox0 = tx0 + pxpair * 2;
  int hl = qy >> 1;                     // local input row base
  int sh = qy & 1;
  int xA = (tx0 >> 1) + pxpair;         // global input col = ox0/2
  int ysrc = oy >> 1;

  // 50 weights: the q-pair for this output pixel pair (issued before barrier;
  // latency hides under the staging drain)
  const float* wq0 = wbuf + ((size_t)(n * 4 + sh * 2 + 0) * HW + ysrc * 64 + xA) * 25;
  const float* wq1 = wbuf + ((size_t)(n * 4 + sh * 2 + 1) * HW + ysrc * 64 + xA) * 25;
  float w0r[25], w1r[25];
#pragma unroll
  for (int k = 0; k < 25; ++k) { w0r[k] = wq0[k]; w1r[k] = wq1[k]; }
#pragma unroll
  for (int k = 0; k < 25; ++k)
    asm volatile("" : "+v"(w0r[k]), "+v"(w1r[k]));   // pin in VGPRs

  __syncthreads();

  float* outb = out + ((size_t)(n * CI + cg * 128) * HS + oy) * WS_ + ox0;
#pragma unroll 2
  for (int it = 0; it < 16; ++it) {
    int cl = it * 8 + cslot;
    const float* p = xpatch + cl * 72 + pxpair;
    float a0 = 0.f, a1 = 0.f;
#pragma unroll
    for (int i = 0; i < 5; ++i) {
      const float* row = p + (hl + i) * 12;
      float f0 = row[0], f1 = row[1], f2 = row[2], f3 = row[3], f4 = row[4];
      a0 = fmaf(f0, w0r[i * 5 + 0], a0); a1 = fmaf(f0, w1r[i * 5 + 0], a1);
      a0 = fmaf(f1, w0r[i * 5 + 1], a0); a1 = fmaf(f1, w1r[i * 5 + 1], a1);
      a0 = fmaf(f2, w0r[i * 5 + 2], a0); a1 = fmaf(f2, w1r[i * 5 + 2], a1);
      a0 = fmaf(f3, w0r[i * 5 + 3], a0); a1 = fmaf(f3, w1r[i * 5 + 3], a1);
      a0 = fmaf(f4, w0r[i * 5 + 4], a0); a1 = fmaf(f4, w1r[i * 5 + 4], a1);
    }
    *(float2*)(outb + (size_t)cl * HS * WS_) = make_float2(a0, a1);
  }
}

// ---------------------------------------------------------------------------
extern "C" void kernel_launch(void* const* d_in, const int* in_sizes, int n_in,
                              void* d_out, int out_size, void* d_ws,
                              size_t ws_size, hipStream_t stream) {
  const float* x      = (const float*)d_in[0];
  const float* w_comp = (const float*)d_in[1];
  const float* b_comp = (const float*)d_in[2];
  const float* w_enc  = (const float*)d_in[3];
  const float* b_enc  = (const float*)d_in[4];
  float* out = (float*)d_out;

  char* ws = (char*)d_ws;
  unsigned short* comp_cl = (unsigned short*)ws;                  // 2,097,152 B
  unsigned short* Aw1     = (unsigned short*)(ws + 2097152);      //    32,768 B
  unsigned short* Aw2     = (unsigned short*)(ws + 2129920);      //   129,024 B
  float*          wbuf_q  = (float*)(ws + 2359296);               // 6,553,600 B

  prep_kernel<<<dim3(316), 256, 0, stream>>>(w_comp, w_enc, Aw1, Aw2);
  conv1x1_mfma<<<dim3(256), 512, 0, stream>>>(x, Aw1, b_comp, comp_cl);
  kenc_mfma<<<dim3(256), 512, 0, stream>>>(comp_cl, Aw2, b_enc, wbuf_q);
  reassembly_kernel<<<dim3(2048), 256, 0, stream>>>(x, wbuf_q, out);
}

// Round 5
// 73.790 us; speedup vs baseline: 1.1982x; 1.1982x over previous
//
#include <hip/hip_runtime.h>

// Problem constants
#define NB 4      // batch
#define CI 256    // input channels
#define HH 64
#define WW 64
#define MC 64     // compressed channels
#define HS 128    // H*2
#define WS_ 128   // W*2
#define HW 4096   // HH*WW
#define WSTR 28   // wbuf per-pixel stride (floats): 112B = 7*16B -> f4-aligned

typedef __attribute__((ext_vector_type(8))) short short8v;   // 8 bf16 (4 VGPRs)
typedef __attribute__((ext_vector_type(4))) float floatx4;   // MFMA C/D

__device__ inline unsigned short f2bf(float f) {
  union { float f; unsigned u; } v; v.f = f;
  unsigned r = v.u + 0x7FFFu + ((v.u >> 16) & 1u);   // RNE
  return (unsigned short)(r >> 16);
}

// ---------------------------------------------------------------------------
// Prep: rearrange weights into MFMA A-fragment layout (bf16).
// ---------------------------------------------------------------------------
__global__ __launch_bounds__(256) void prep_kernel(
    const float* __restrict__ w_comp, const float* __restrict__ w_enc,
    unsigned short* __restrict__ Aw1, unsigned short* __restrict__ Aw2) {
  int i = blockIdx.x * 256 + threadIdx.x;
  if (i < 16384) {                       // 8*64*32
    int kl = i & 31, o = (i >> 5) & 63, ks = i >> 11;
    Aw1[i] = f2bf(w_comp[o * 256 + ks * 32 + kl]);
  } else if (i < 16384 + 64512) {        // 18*112*32
    int j = i - 16384;
    int kl = j & 31, o = (j >> 5) % 112, ks = (j >> 5) / 112;
    int t = ks >> 1, m = (ks & 1) * 32 + kl;
    Aw2[j] = (o < 100) ? f2bf(w_enc[o * 576 + m * 9 + t]) : (unsigned short)0;
  }
}

// ---------------------------------------------------------------------------
// Kernel 1: 1x1 conv via MFMA, K-split 2 (unchanged from round 4).
// ---------------------------------------------------------------------------
__global__ __launch_bounds__(512, 1) void conv1x1_mfma(
    const float* __restrict__ x, const unsigned short* __restrict__ Aw1,
    const float* __restrict__ b_comp, unsigned short* __restrict__ comp_cl) {
  __shared__ float pacc[4][64][17];
  int tid = threadIdx.x;
  int wid = tid >> 6, lane = tid & 63;
  int tileid = wid & 3, kh = wid >> 2;
  int Nt = blockIdx.x * 4 + tileid;       // 0..1023
  int n = Nt >> 8, pixbase = (Nt & 255) * 16;
  int l15 = lane & 15, g = lane >> 4;
  int pix = pixbase + l15;

  floatx4 acc[4];
#pragma unroll
  for (int ot = 0; ot < 4; ++ot) acc[ot] = (floatx4){0.f, 0.f, 0.f, 0.f};

  const float* xb = x + (size_t)n * CI * HW + pix;
  const unsigned short* ab = Aw1 + l15 * 32 + g * 8;

#pragma unroll
  for (int s = 0; s < 4; ++s) {
    int ks = kh * 4 + s;
    int c0 = ks * 32 + g * 8;
    short8v bfrag;
#pragma unroll
    for (int j = 0; j < 8; ++j)
      bfrag[j] = (short)f2bf(xb[(size_t)(c0 + j) * HW]);
#pragma unroll
    for (int ot = 0; ot < 4; ++ot) {
      short8v af = *(const short8v*)(ab + (ks * 64 + ot * 16) * 32);
      acc[ot] = __builtin_amdgcn_mfma_f32_16x16x32_bf16(af, bfrag, acc[ot], 0, 0, 0);
    }
  }

  if (kh == 1) {
#pragma unroll
    for (int ot = 0; ot < 4; ++ot)
#pragma unroll
      for (int r = 0; r < 4; ++r) pacc[tileid][lane][ot * 4 + r] = acc[ot][r];
  }
  __syncthreads();
  if (kh == 0) {
    unsigned short* cp = comp_cl + ((size_t)(n * HW + pix)) * 64;
#pragma unroll
    for (int ot = 0; ot < 4; ++ot) {
      const float4 bv = *(const float4*)(b_comp + ot * 16 + g * 4);
      float v0 = acc[ot][0] + pacc[tileid][lane][ot * 4 + 0] + bv.x;
      float v1 = acc[ot][1] + pacc[tileid][lane][ot * 4 + 1] + bv.y;
      float v2 = acc[ot][2] + pacc[tileid][lane][ot * 4 + 2] + bv.z;
      float v3 = acc[ot][3] + pacc[tileid][lane][ot * 4 + 3] + bv.w;
      unsigned h01 = (unsigned)f2bf(v0) | ((unsigned)f2bf(v1) << 16);
      unsigned h23 = (unsigned)f2bf(v2) | ((unsigned)f2bf(v3) << 16);
      *(int2*)(cp + ot * 16 + g * 4) = make_int2((int)h01, (int)h23);
    }
  }
}

// ---------------------------------------------------------------------------
// Kernel 2: 3x3 conv + pixel-shuffle + softmax(25), K-split 2.
// Only change: wbuf pixel stride 25 -> WSTR(28) for 16B-aligned f4 reads.
// ---------------------------------------------------------------------------
__global__ __launch_bounds__(512, 1) void kenc_mfma(
    const unsigned short* __restrict__ comp_cl,
    const unsigned short* __restrict__ Aw2,
    const float* __restrict__ b_enc, float* __restrict__ wbuf_q) {
  __shared__ float pacc[4][64][29];
  int tid = threadIdx.x;
  int wid = tid >> 6, lane = tid & 63;
  int tileid = wid & 3, kh = wid >> 2;
  int Nt = blockIdx.x * 4 + tileid;       // 0..1023
  int n = Nt >> 8, pixbase = (Nt & 255) * 16;
  int l15 = lane & 15, g = lane >> 4;
  int pix = pixbase + l15;
  int y = pix >> 6, xcol = pix & 63;

  bool vm[9];
  int sh9[9];
#pragma unroll
  for (int t = 0; t < 9; ++t) {
    int dy = t / 3, dx = t % 3;
    vm[t] = ((unsigned)(y + dy - 1) < 64u) && ((unsigned)(xcol + dx - 1) < 64u);
    sh9[t] = (dy - 1) * 64 + (dx - 1);
  }

  floatx4 acc[7];
#pragma unroll
  for (int ot = 0; ot < 7; ++ot) acc[ot] = (floatx4){0.f, 0.f, 0.f, 0.f};

  const unsigned short* cb = comp_cl + (size_t)n * HW * 64;
  const unsigned short* ab = Aw2 + l15 * 32 + g * 8;
  const short8v zv = {0, 0, 0, 0, 0, 0, 0, 0};

#pragma unroll
  for (int s = 0; s < 9; ++s) {
    int ks = kh * 9 + s;
    int t = ks >> 1, mh = ks & 1;
    const unsigned short* bp = cb + (pix + sh9[t]) * 64 + mh * 32 + g * 8;
    short8v bfrag = vm[t] ? *(const short8v*)bp : zv;
#pragma unroll
    for (int ot = 0; ot < 7; ++ot) {
      short8v af = *(const short8v*)(ab + (ks * 112 + ot * 16) * 32);
      acc[ot] = __builtin_amdgcn_mfma_f32_16x16x32_bf16(af, bfrag, acc[ot], 0, 0, 0);
    }
  }

  if (kh == 1) {
#pragma unroll
    for (int ot = 0; ot < 7; ++ot)
#pragma unroll
      for (int r = 0; r < 4; ++r) pacc[tileid][lane][ot * 4 + r] = acc[ot][r];
  }
  __syncthreads();
  if (kh == 0) {
#pragma unroll
    for (int ot = 0; ot < 7; ++ot) {
      int ob = ot * 16 + g * 4; if (ob > 96) ob = 96;
      const float4 bv = *(const float4*)(b_enc + ob);
      acc[ot][0] += pacc[tileid][lane][ot * 4 + 0] + bv.x;
      acc[ot][1] += pacc[tileid][lane][ot * 4 + 1] + bv.y;
      acc[ot][2] += pacc[tileid][lane][ot * 4 + 2] + bv.z;
      acc[ot][3] += pacc[tileid][lane][ot * 4 + 3] + bv.w;
    }

#pragma unroll
    for (int r = 0; r < 4; ++r) {
      float m = acc[0][r];
#pragma unroll
      for (int ot = 1; ot < 6; ++ot) m = fmaxf(m, acc[ot][r]);
      if (g == 0) m = fmaxf(m, acc[6][r]);
      m = fmaxf(m, __shfl_xor(m, 16));
      m = fmaxf(m, __shfl_xor(m, 32));
      float s = 0.f;
      float e[7];
#pragma unroll
      for (int ot = 0; ot < 7; ++ot) {
        bool val = (ot < 6) || (g == 0);
        e[ot] = val ? __expf(acc[ot][r] - m) : 0.f;
        s += e[ot];
      }
      s += __shfl_xor(s, 16);
      s += __shfl_xor(s, 32);
      float inv = 1.f / s;
      float* wq = wbuf_q + ((size_t)(n * 4 + r) * HW + pix) * WSTR;
#pragma unroll
      for (int ot = 0; ot < 7; ++ot)
        if ((ot < 6) || (g == 0)) wq[ot * 4 + g] = e[ot] * inv;
    }
  }
}

// ---------------------------------------------------------------------------
// Kernel 3: reassembly v4 = v2 mapping (4 outputs/thread, 15 b64-reads per
// 100 FMA) + resident weights: f4 loads from stride-28 wbuf, asm-pinned,
// launch_bounds(256,4) (cap 128 VGPR). Stage -> weight loads -> pin ->
// barrier so weight latency hides under the staging drain.
// ---------------------------------------------------------------------------
__global__ __launch_bounds__(256, 4) void reassembly_kernel(
    const float* __restrict__ x, const float* __restrict__ wbuf,
    float* __restrict__ out) {
  __shared__ float xpatch[128 * 72];    // [c][r:6][col:12]
  int tid = threadIdx.x;
  int bid = blockIdx.x;                 // tile(256) | n(4) | cg(2)
  int tile = bid & 255;
  int n = (bid >> 8) & 3;
  int cg = bid >> 10;
  int tyi = tile >> 3, txi = tile & 7;  // 32 x 8 tiles of 4x16 outputs
  int ty0 = tyi * 4, tx0 = txi * 16;
  int h0 = ty0 >> 1, w0 = tx0 >> 1;

  const float* xb = x + (size_t)(n * CI + cg * 128) * HW;
  bool interior = (tyi >= 1) && (tyi <= 30) && (txi >= 1) && (txi <= 6);

  if (interior) {
#pragma unroll
    for (int j = 0; j < 9; ++j) {
      int f = tid + 256 * j;            // f4 index 0..2303 (128*18)
      int c = f / 18, rem = f - c * 18;
      int r = rem / 3, h = rem - r * 3;
      const float* gp = xb + (size_t)c * HW + (h0 - 2 + r) * WW + (w0 - 2 + h * 4);
      float2 lo = *(const float2*)(gp);
      float2 hi = *(const float2*)(gp + 2);
      *(float4*)(xpatch + c * 72 + r * 12 + h * 4) =
          make_float4(lo.x, lo.y, hi.x, hi.y);
    }
  } else {
#pragma unroll
    for (int j = 0; j < 9; ++j) {
      int f = tid + 256 * j;
      int c = f / 18, rem = f - c * 18;
      int r = rem / 3, h = rem - r * 3;
      int gh = h0 - 2 + r;
      float vv[4];
#pragma unroll
      for (int e = 0; e < 4; ++e) {
        int gw = w0 - 2 + h * 4 + e;
        vv[e] = (((unsigned)gh < 64u) && ((unsigned)gw < 64u))
                    ? xb[(size_t)c * HW + gh * WW + gw] : 0.f;
      }
      *(float4*)(xpatch + c * 72 + r * 12 + h * 4) =
          make_float4(vv[0], vv[1], vv[2], vv[3]);
    }
  }

  // Thread mapping (v2): 16 channel-slots x 16 pixel-quads
  int cslot = tid >> 4;                 // 0..15
  int quad  = tid & 15;                 // qy(2b) | qx(2b)
  int qy = quad >> 2, qx = quad & 3;
  int oy = ty0 + qy;
  int ox0 = tx0 + qx * 4;
  int hl = qy >> 1;                     // local input row base
  int ix0 = qx * 2;                     // local patch col base
  int sh = qy & 1;
  int xA = ox0 >> 1;                    // global input col of first pixel
  int ysrc = oy >> 1;

  // Weight loads (after staging issue; latency hides under barrier drain).
  // 100 weights = 2 q-planes x 2 adjacent pixels x 25, f4 from stride-28 wbuf.
  const float* wq0 = wbuf + ((size_t)(n * 4 + sh * 2 + 0) * HW + ysrc * 64 + xA) * WSTR;
  const float* wq1 = wbuf + ((size_t)(n * 4 + sh * 2 + 1) * HW + ysrc * 64 + xA) * WSTR;
  float wreg[100];
#pragma unroll
  for (int g4 = 0; g4 < 6; ++g4) {
    *(float4*)(&wreg[g4 * 4])      = *(const float4*)(wq0 + g4 * 4);
    *(float4*)(&wreg[25 + g4 * 4]) = *(const float4*)(wq1 + g4 * 4);
    *(float4*)(&wreg[50 + g4 * 4]) = *(const float4*)(wq0 + WSTR + g4 * 4);
    *(float4*)(&wreg[75 + g4 * 4]) = *(const float4*)(wq1 + WSTR + g4 * 4);
  }
  wreg[24] = wq0[24]; wreg[49] = wq1[24];
  wreg[74] = wq0[WSTR + 24]; wreg[99] = wq1[WSTR + 24];
#pragma unroll
  for (int k = 0; k < 100; ++k)
    asm volatile("" : "+v"(wreg[k]));   // force residency (defeat load sinking)

  __syncthreads();

  float* outb = out + ((size_t)(n * CI + cg * 128) * HS + oy) * WS_ + ox0;
  for (int it = 0; it < 8; ++it) {
    int cl = it * 16 + cslot;
    const float* p = xpatch + cl * 72 + ix0;
    float a0 = 0.f, a1 = 0.f, a2 = 0.f, a3 = 0.f;
#pragma unroll
    for (int i = 0; i < 5; ++i) {
      const float* row = p + (hl + i) * 12;
      float2 f01 = *(const float2*)(row);
      float2 f23 = *(const float2*)(row + 2);
      float2 f45 = *(const float2*)(row + 4);
      float f[6] = {f01.x, f01.y, f23.x, f23.y, f45.x, f45.y};
#pragma unroll
      for (int j = 0; j < 5; ++j) {
        a0 = fmaf(f[j],     wreg[i * 5 + j],      a0);
        a1 = fmaf(f[j],     wreg[25 + i * 5 + j], a1);
        a2 = fmaf(f[j + 1], wreg[50 + i * 5 + j], a2);
        a3 = fmaf(f[j + 1], wreg[75 + i * 5 + j], a3);
      }
    }
    *(float4*)(outb + (size_t)cl * HS * WS_) = make_float4(a0, a1, a2, a3);
  }
}

// ---------------------------------------------------------------------------
extern "C" void kernel_launch(void* const* d_in, const int* in_sizes, int n_in,
                              void* d_out, int out_size, void* d_ws,
                              size_t ws_size, hipStream_t stream) {
  const float* x      = (const float*)d_in[0];
  const float* w_comp = (const float*)d_in[1];
  const float* b_comp = (const float*)d_in[2];
  const float* w_enc  = (const float*)d_in[3];
  const float* b_enc  = (const float*)d_in[4];
  float* out = (float*)d_out;

  char* ws = (char*)d_ws;
  unsigned short* comp_cl = (unsigned short*)ws;                  // 2,097,152 B
  unsigned short* Aw1     = (unsigned short*)(ws + 2097152);      //    32,768 B
  unsigned short* Aw2     = (unsigned short*)(ws + 2129920);      //   129,024 B
  float*          wbuf_q  = (float*)(ws + 2359296);               // 7,340,032 B

  prep_kernel<<<dim3(316), 256, 0, stream>>>(w_comp, w_enc, Aw1, Aw2);
  conv1x1_mfma<<<dim3(256), 512, 0, stream>>>(x, Aw1, b_comp, comp_cl);
  kenc_mfma<<<dim3(256), 512, 0, stream>>>(comp_cl, Aw2, b_enc, wbuf_q);
  reassembly_kernel<<<dim3(2048), 256, 0, stream>>>(x, wbuf_q, out);
}